// Round 2
// baseline (170.720 us; speedup 1.0000x reference)
//
#include <hip/hip_runtime.h>
#include <stdint.h>

#define N_ROWS 4096
#define D_DIM  1024
#define ROWB   1024   // bytes per row in fp8
#define T_TEMP 0.15f

typedef float f32x4  __attribute__((ext_vector_type(4)));
typedef int   i32x4v __attribute__((ext_vector_type(4)));
typedef int   i32x8  __attribute__((ext_vector_type(8)));

__device__ __forceinline__ float wsum(float v) {
#pragma unroll
  for (int m = 32; m >= 1; m >>= 1) v += __shfl_xor(v, m, 64);
  return v;
}
__device__ __forceinline__ float wmax(float v) {
#pragma unroll
  for (int m = 32; m >= 1; m >>= 1) v = fmaxf(v, __shfl_xor(v, m, 64));
  return v;
}

// One WAVE per row (no barriers): norms, x.y dot (-> log pos), softmax-JS
// terms, fp8-e4m3 casts of x and y into Bb = [x;y] (8192 x 1024 fp8).
__global__ __launch_bounds__(256) void prep_kernel(
    const float* __restrict__ x, const float* __restrict__ y,
    unsigned char* __restrict__ Bb, float* __restrict__ inv_n,
    float* __restrict__ logpos, float* __restrict__ js_acc) {
  const int wid = threadIdx.x >> 6, lane = threadIdx.x & 63;
  const int row = blockIdx.x * 4 + wid;
  const float4* xp = (const float4*)(x + (size_t)row * D_DIM) + lane * 4;
  const float4* yp = (const float4*)(y + (size_t)row * D_DIM) + lane * 4;

  float xv[16], yv[16];
#pragma unroll
  for (int i = 0; i < 4; ++i) {
    float4 a = xp[i], b = yp[i];
    xv[i*4+0]=a.x; xv[i*4+1]=a.y; xv[i*4+2]=a.z; xv[i*4+3]=a.w;
    yv[i*4+0]=b.x; yv[i*4+1]=b.y; yv[i*4+2]=b.z; yv[i*4+3]=b.w;
  }

  float sx2=0.f, sy2=0.f, sxy=0.f, mx=-1e30f, my=-1e30f;
#pragma unroll
  for (int k = 0; k < 16; ++k) {
    sx2 = fmaf(xv[k], xv[k], sx2);
    sy2 = fmaf(yv[k], yv[k], sy2);
    sxy = fmaf(xv[k], yv[k], sxy);
    mx = fmaxf(mx, xv[k]); my = fmaxf(my, yv[k]);
  }
  sx2 = wsum(sx2); sy2 = wsum(sy2); sxy = wsum(sxy);
  mx = wmax(mx);  my = wmax(my);

  float ex[16], ey[16], sex=0.f, sey=0.f;
#pragma unroll
  for (int k = 0; k < 16; ++k) {
    ex[k] = __expf(xv[k] - mx); ey[k] = __expf(yv[k] - my);
    sex += ex[k]; sey += ey[k];
  }
  sex = wsum(sex); sey = wsum(sey);
  const float lsex = __logf(sex), lsey = __logf(sey);
  const float rsex = 1.f / sex,  rsey = 1.f / sey;

  float term = 0.f;
#pragma unroll
  for (int k = 0; k < 16; ++k) {
    float a = ex[k] * rsex, b = ey[k] * rsey;
    float lm = __logf(0.5f * (a + b));
    term += a * ((xv[k] - mx - lsex) - lm) + b * ((yv[k] - my - lsey) - lm);
  }
  term = wsum(term);

  if (lane == 0) {
    const float nx = sqrtf(sx2), ny = sqrtf(sy2);
    inv_n[row] = 1.f / nx;
    inv_n[N_ROWS + row] = 1.f / ny;
    logpos[row] = sxy / fmaxf(nx * ny, 1e-8f) / T_TEMP;  // ln(pos)
    atomicAdd(js_acc, term);
  }

  int p[4], q[4];
#pragma unroll
  for (int w = 0; w < 4; ++w) {
    int v = 0;
    v = __builtin_amdgcn_cvt_pk_fp8_f32(xv[w*4+0], xv[w*4+1], v, false);
    v = __builtin_amdgcn_cvt_pk_fp8_f32(xv[w*4+2], xv[w*4+3], v, true);
    p[w] = v;
    int u = 0;
    u = __builtin_amdgcn_cvt_pk_fp8_f32(yv[w*4+0], yv[w*4+1], u, false);
    u = __builtin_amdgcn_cvt_pk_fp8_f32(yv[w*4+2], yv[w*4+3], u, true);
    q[w] = u;
  }
  *(int4*)(Bb + (size_t)row * ROWB + lane * 16) = make_int4(p[0], p[1], p[2], p[3]);
  *(int4*)(Bb + (size_t)(N_ROWS + row) * ROWB + lane * 16) = make_int4(q[0], q[1], q[2], q[3]);
}

// frag read: lane's 32 fp8 of row r at k = hi*32..hi*32+31, slots XOR-swizzled by row&7
__device__ __forceinline__ i32x8 frag8(const char* rowbase, int s0) {
  i32x4v p0 = *(const i32x4v*)(rowbase + s0 * 16);
  i32x4v p1 = *(const i32x4v*)(rowbase + (s0 ^ 1) * 16);
  i32x8 r;
  r[0]=p0[0]; r[1]=p0[1]; r[2]=p0[2]; r[3]=p0[3];
  r[4]=p1[0]; r[5]=p1[1]; r[6]=p1[2]; r[7]=p1[3];
  return r;
}

// Fused MX-fp8 GEMM (unit scales): A = rows [0,4096) of Bb, B = all 8192 rows.
// 128x128 tile, BK=128 fp8, 4 waves. Epilogue: exp2 -> diag-mask -> row-sum -> atomic.
__global__ __launch_bounds__(256) void gemm_fused(
    const unsigned char* __restrict__ Bb, const float* __restrict__ inv_n,
    float* __restrict__ rowsum) {
  __shared__ __align__(16) char As[128 * 128];
  __shared__ __align__(16) char Bs[128 * 128];
  const int tid = threadIdx.x;
  const int wid = tid >> 6, lane = tid & 63;
  const int lo = lane & 15, hi = lane >> 4;
  const int grow0 = blockIdx.x * 128;
  const int gcol0 = blockIdx.y * 128;
  const int wrow = (wid >> 1) * 64, wcol = (wid & 1) * 64;

  f32x4 acc[4][4] = {};

  // staging: 4 global_load_lds per matrix per K-step; each covers 32 rows.
  // LDS is linear [row][128B]; the 16B-chunk index is XOR-swizzled via the
  // GLOBAL source (rule: swizzle both sides or neither).
  const int l3 = lane >> 3;                 // row-within-8 = (LDS row)&7
  const int chunk = (lane & 7) ^ l3;        // pre-swizzled global 16B chunk
  const unsigned char* gA = Bb + (size_t)(grow0 + wid * 8 + l3) * ROWB + chunk * 16;
  const unsigned char* gB = Bb + (size_t)(gcol0 + wid * 8 + l3) * ROWB + chunk * 16;

  for (int kt = 0; kt < 8; ++kt) {
    __syncthreads();   // prior ds_reads done before overwrite
#pragma unroll
    for (int i = 0; i < 4; ++i) {
      __builtin_amdgcn_global_load_lds(
          (const __attribute__((address_space(1))) void*)(gA + (size_t)i * 32 * ROWB + kt * 128),
          (__attribute__((address_space(3))) void*)(As + i * 4096 + wid * 1024), 16, 0, 0);
      __builtin_amdgcn_global_load_lds(
          (const __attribute__((address_space(1))) void*)(gB + (size_t)i * 32 * ROWB + kt * 128),
          (__attribute__((address_space(3))) void*)(Bs + i * 4096 + wid * 1024), 16, 0, 0);
    }
    __syncthreads();   // staging visible (compiler drains vmcnt before barrier)

    i32x8 af[4], bfr[4];
    const int e = lo & 7;
#pragma unroll
    for (int m = 0; m < 4; ++m)
      af[m] = frag8(As + (wrow + m * 16 + lo) * 128, (2 * hi) ^ e);
#pragma unroll
    for (int n = 0; n < 4; ++n)
      bfr[n] = frag8(Bs + (wcol + n * 16 + lo) * 128, (2 * hi) ^ e);
#pragma unroll
    for (int m = 0; m < 4; ++m)
#pragma unroll
      for (int n = 0; n < 4; ++n)
        acc[m][n] = __builtin_amdgcn_mfma_scale_f32_16x16x128_f8f6f4(
            af[m], bfr[n], acc[m][n], 0, 0,          // cbsz=fp8, blgp=fp8
            0, 0x7F7F7F7F, 0, 0x7F7F7F7F);           // unit E8M0 scales
  }

  // epilogue: scale -> exp2 -> mask diag -> row-reduce -> atomic
  const float C = 1.4426950408889634f / T_TEMP;   // log2(e)/T
  float invc[4], invr[4][4];
#pragma unroll
  for (int n = 0; n < 4; ++n)
    invc[n] = inv_n[gcol0 + wcol + n * 16 + lo] * C;
#pragma unroll
  for (int m = 0; m < 4; ++m)
#pragma unroll
    for (int r = 0; r < 4; ++r)
      invr[m][r] = inv_n[grow0 + wrow + m * 16 + hi * 4 + r];

  float rp[4][4] = {};
#pragma unroll
  for (int m = 0; m < 4; ++m)
#pragma unroll
    for (int n = 0; n < 4; ++n)
#pragma unroll
      for (int r = 0; r < 4; ++r) {
        const int i = grow0 + wrow + m * 16 + hi * 4 + r;
        const int j = gcol0 + wcol + n * 16 + lo;
        float e2 = exp2f(acc[m][n][r] * invr[m][r] * invc[n]);
        if (j == i || j == i + N_ROWS) e2 = 0.0f;
        rp[m][r] += e2;
      }

#pragma unroll
  for (int m = 0; m < 4; ++m)
#pragma unroll
    for (int r = 0; r < 4; ++r) {
      float v = rp[m][r];
      v += __shfl_xor(v, 1, 16);
      v += __shfl_xor(v, 2, 16);
      v += __shfl_xor(v, 4, 16);
      v += __shfl_xor(v, 8, 16);
      if (lo == 0)
        atomicAdd(&rowsum[grow0 + wrow + m * 16 + hi * 4 + r], v);
    }
}

// Single block: cumsum(rowsum) -> sum(log(neg) - logpos) + js -> out[0]
__global__ __launch_bounds__(256) void final_kernel(
    const float* __restrict__ rowsum, const float* __restrict__ logpos,
    const float* __restrict__ js_acc, float* __restrict__ out) {
  __shared__ float scan[256];
  __shared__ double ds[4];
  const int tid = threadIdx.x;
  float loc[16];
  float run = 0.f;
#pragma unroll
  for (int k = 0; k < 16; ++k) { loc[k] = rowsum[tid * 16 + k]; run += loc[k]; }
  scan[tid] = run;
  __syncthreads();
  for (int d = 1; d < 256; d <<= 1) {
    float add = (tid >= d) ? scan[tid - d] : 0.0f;
    __syncthreads();
    scan[tid] += add;
    __syncthreads();
  }
  float c = scan[tid] - run;  // exclusive prefix
  double acc = 0.0;
#pragma unroll
  for (int k = 0; k < 16; ++k) {
    c += loc[k];
    acc += (double)(logf(c) - logpos[tid * 16 + k]);
  }
#pragma unroll
  for (int m = 32; m >= 1; m >>= 1) acc += __shfl_xor(acc, m, 64);
  if ((tid & 63) == 0) ds[tid >> 6] = acc;
  __syncthreads();
  if (tid == 0) {
    const double nce = ds[0] + ds[1] + ds[2] + ds[3];
    const double js = (double)js_acc[0] / (2.0 * N_ROWS);
    out[0] = (float)(nce + 1.0 * js);
  }
}

extern "C" void kernel_launch(void* const* d_in, const int* in_sizes, int n_in,
                              void* d_out, int out_size, void* d_ws, size_t ws_size,
                              hipStream_t stream) {
  const float* x = (const float*)d_in[0];
  const float* y = (const float*)d_in[1];
  float* out = (float*)d_out;

  char* ws = (char*)d_ws;
  unsigned char* Bb = (unsigned char*)ws;                  // [8192][1024] fp8, 8 MB
  float* inv_n  = (float*)(ws + (size_t)8 * 1024 * 1024);  // 8192
  float* logpos = inv_n + 8192;                            // 4096
  float* rowsum = logpos + 4096;                           // 4096
  float* js_acc = rowsum + 4096;                           // 1

  hipMemsetAsync(rowsum, 0, (4096 + 1) * sizeof(float), stream);
  prep_kernel<<<N_ROWS / 4, 256, 0, stream>>>(x, y, Bb, inv_n, logpos, js_acc);
  gemm_fused<<<dim3(32, 64), 256, 0, stream>>>(Bb, inv_n, rowsum);
  final_kernel<<<1, 256, 0, stream>>>(rowsum, logpos, js_acc, out);
}

// Round 3
// 153.960 us; speedup vs baseline: 1.1089x; 1.1089x over previous
//
#include <hip/hip_runtime.h>
#include <stdint.h>

#define N_ROWS 4096
#define D_DIM  1024
#define KBYTES 2048   // bytes per row in bf16
#define T_TEMP 0.15f

typedef float  f32x4  __attribute__((ext_vector_type(4)));
typedef __bf16 bf16x8 __attribute__((ext_vector_type(8)));

__device__ __forceinline__ unsigned int f2bf(float f) {
  unsigned u = __float_as_uint(f);
  u += 0x7FFF + ((u >> 16) & 1);   // RNE
  return u >> 16;
}

__device__ __forceinline__ float wsum(float v) {
#pragma unroll
  for (int m = 32; m >= 1; m >>= 1) v += __shfl_xor(v, m, 64);
  return v;
}
__device__ __forceinline__ float wmax(float v) {
#pragma unroll
  for (int m = 32; m >= 1; m >>= 1) v = fmaxf(v, __shfl_xor(v, m, 64));
  return v;
}

// One WAVE per row (no barriers): norms, x.y dot (-> log pos), softmax-JS
// terms, bf16 casts of x and y into Bb = [x;y] (8192 x 1024 bf16).
__global__ __launch_bounds__(256) void prep_kernel(
    const float* __restrict__ x, const float* __restrict__ y,
    unsigned short* __restrict__ Bb, float* __restrict__ inv_n,
    float* __restrict__ logpos, float* __restrict__ js_acc) {
  const int wid = threadIdx.x >> 6, lane = threadIdx.x & 63;
  const int row = blockIdx.x * 4 + wid;
  const float4* xp = (const float4*)(x + (size_t)row * D_DIM) + lane * 4;
  const float4* yp = (const float4*)(y + (size_t)row * D_DIM) + lane * 4;

  float xv[16], yv[16];
#pragma unroll
  for (int i = 0; i < 4; ++i) {
    float4 a = xp[i], b = yp[i];
    xv[i*4+0]=a.x; xv[i*4+1]=a.y; xv[i*4+2]=a.z; xv[i*4+3]=a.w;
    yv[i*4+0]=b.x; yv[i*4+1]=b.y; yv[i*4+2]=b.z; yv[i*4+3]=b.w;
  }

  float sx2=0.f, sy2=0.f, sxy=0.f, mx=-1e30f, my=-1e30f;
#pragma unroll
  for (int k = 0; k < 16; ++k) {
    sx2 = fmaf(xv[k], xv[k], sx2);
    sy2 = fmaf(yv[k], yv[k], sy2);
    sxy = fmaf(xv[k], yv[k], sxy);
    mx = fmaxf(mx, xv[k]); my = fmaxf(my, yv[k]);
  }
  sx2 = wsum(sx2); sy2 = wsum(sy2); sxy = wsum(sxy);
  mx = wmax(mx);  my = wmax(my);

  float ex[16], ey[16], sex=0.f, sey=0.f;
#pragma unroll
  for (int k = 0; k < 16; ++k) {
    ex[k] = __expf(xv[k] - mx); ey[k] = __expf(yv[k] - my);
    sex += ex[k]; sey += ey[k];
  }
  sex = wsum(sex); sey = wsum(sey);
  const float lsex = __logf(sex), lsey = __logf(sey);
  const float rsex = 1.f / sex,  rsey = 1.f / sey;

  float term = 0.f;
#pragma unroll
  for (int k = 0; k < 16; ++k) {
    float a = ex[k] * rsex, b = ey[k] * rsey;
    float lm = __logf(0.5f * (a + b));
    term += a * ((xv[k] - mx - lsex) - lm) + b * ((yv[k] - my - lsey) - lm);
  }
  term = wsum(term);

  if (lane == 0) {
    const float nx = sqrtf(sx2), ny = sqrtf(sy2);
    inv_n[row] = 1.f / nx;
    inv_n[N_ROWS + row] = 1.f / ny;
    logpos[row] = sxy / fmaxf(nx * ny, 1e-8f) / T_TEMP;  // ln(pos)
    atomicAdd(js_acc, term);
  }

  int p[8], q[8];
#pragma unroll
  for (int w = 0; w < 8; ++w) {
    p[w] = f2bf(xv[2*w]) | (f2bf(xv[2*w+1]) << 16);
    q[w] = f2bf(yv[2*w]) | (f2bf(yv[2*w+1]) << 16);
  }
  int4* ox = (int4*)(Bb + (size_t)row * D_DIM + lane * 16);
  int4* oy = (int4*)(Bb + (size_t)(N_ROWS + row) * D_DIM + lane * 16);
  ox[0] = make_int4(p[0], p[1], p[2], p[3]);
  ox[1] = make_int4(p[4], p[5], p[6], p[7]);
  oy[0] = make_int4(q[0], q[1], q[2], q[3]);
  oy[1] = make_int4(q[4], q[5], q[6], q[7]);
}

// Fused GEMM over needed tiles only. A = rows [0,4096) of Bb (=x),
// B = all 8192 rows (=[x;y]). 1D grid: idx<1024 -> Sxy tile (bi, 32+bj');
// else upper-triangle Sxx tile (bi<=bj<32). For bi<bj symmetric tiles the
// epilogue also adds col-sums to rowsum[cols] (Sxx[j][i] = Sxx[i][j]).
// LDS chunk-XOR swizzle (both sides: pre-swizzled global src for
// global_load_lds + swizzled ds_read addr) kills the 8-way bank conflict.
__global__ __launch_bounds__(256) void gemm_fused(
    const unsigned short* __restrict__ Bb, const float* __restrict__ inv_n,
    float* __restrict__ rowsum) {
  __shared__ __align__(16) unsigned short As[128 * 32];
  __shared__ __align__(16) unsigned short Bs[128 * 32];
  const int tid = threadIdx.x;
  const int wid = tid >> 6, lane = tid & 63;
  const int lo = lane & 15, hi = lane >> 4;

  int bi, bj;
  bool sym = false;
  {
    const int idx = blockIdx.x;
    if (idx < 1024) {
      bi = idx >> 5; bj = 32 + (idx & 31);
    } else {
      const int t = idx - 1024;
      int b = (int)((65.0 - sqrt((double)(4225 - 8 * t))) * 0.5);
      while ((b + 1) * (65 - (b + 1)) / 2 <= t) ++b;
      while (b * (65 - b) / 2 > t) --b;
      bi = b;
      bj = b + (t - b * (65 - b) / 2);
      sym = (bi != bj);
    }
  }
  const int grow0 = bi * 128;
  const int gcol0 = bj * 128;
  const int wrow = (wid >> 1) * 64, wcol = (wid & 1) * 64;

  f32x4 acc[4][4] = {};

  // staging: LDS row = tid>>2 (64B rows), chunk = tid&3, source chunk
  // pre-swizzled by (row>>1)&3 = (tid>>3)&3.
  const int srow = tid >> 2;
  const int scb  = ((tid & 3) ^ ((tid >> 3) & 3)) * 16;
  const char* gA = (const char*)Bb + (size_t)(grow0 + srow) * KBYTES + scb;
  const char* gB = (const char*)Bb + (size_t)(gcol0 + srow) * KBYTES + scb;
  char* lA = (char*)As + wid * 1024;
  char* lB = (char*)Bs + wid * 1024;

  for (int kt = 0; kt < 32; ++kt) {
    __syncthreads();   // prior ds_reads done before overwrite
    const char* a0 = gA + kt * 64;
    const char* b0 = gB + kt * 64;
    __builtin_amdgcn_global_load_lds((const __attribute__((address_space(1))) void*)a0,
                                     (__attribute__((address_space(3))) void*)lA, 16, 0, 0);
    __builtin_amdgcn_global_load_lds((const __attribute__((address_space(1))) void*)(a0 + (size_t)64 * KBYTES),
                                     (__attribute__((address_space(3))) void*)(lA + 4096), 16, 0, 0);
    __builtin_amdgcn_global_load_lds((const __attribute__((address_space(1))) void*)b0,
                                     (__attribute__((address_space(3))) void*)lB, 16, 0, 0);
    __builtin_amdgcn_global_load_lds((const __attribute__((address_space(1))) void*)(b0 + (size_t)64 * KBYTES),
                                     (__attribute__((address_space(3))) void*)(lB + 4096), 16, 0, 0);
    __syncthreads();   // staging visible (compiler drains vmcnt before barrier)

    bf16x8 af[4], bfg[4];
    const int xr = (lo >> 1) & 3;   // (row>>1)&3 for row = base16 + lo
#pragma unroll
    for (int m = 0; m < 4; ++m)
      af[m] = *(const bf16x8*)&As[(wrow + m * 16 + lo) * 32 + ((hi ^ xr) << 3)];
#pragma unroll
    for (int n = 0; n < 4; ++n)
      bfg[n] = *(const bf16x8*)&Bs[(wcol + n * 16 + lo) * 32 + ((hi ^ xr) << 3)];
#pragma unroll
    for (int m = 0; m < 4; ++m)
#pragma unroll
      for (int n = 0; n < 4; ++n)
        acc[m][n] = __builtin_amdgcn_mfma_f32_16x16x32_bf16(af[m], bfg[n], acc[m][n], 0, 0, 0);
  }

  // epilogue: scale -> exp2 -> mask diag -> row-reduce (+col-reduce if sym)
  const float C = 1.4426950408889634f / T_TEMP;   // log2(e)/T
  float invc[4], invr[4][4];
#pragma unroll
  for (int n = 0; n < 4; ++n)
    invc[n] = inv_n[gcol0 + wcol + n * 16 + lo] * C;
#pragma unroll
  for (int m = 0; m < 4; ++m)
#pragma unroll
    for (int r = 0; r < 4; ++r)
      invr[m][r] = inv_n[grow0 + wrow + m * 16 + hi * 4 + r];

  float rp[4][4] = {};
  float cp[4] = {};
#pragma unroll
  for (int m = 0; m < 4; ++m)
#pragma unroll
    for (int n = 0; n < 4; ++n)
#pragma unroll
      for (int r = 0; r < 4; ++r) {
        const int i = grow0 + wrow + m * 16 + hi * 4 + r;
        const int j = gcol0 + wcol + n * 16 + lo;
        float e2 = exp2f(acc[m][n][r] * invr[m][r] * invc[n]);
        if (j == i || j == i + N_ROWS) e2 = 0.0f;
        rp[m][r] += e2;
        cp[n] += e2;
      }

#pragma unroll
  for (int m = 0; m < 4; ++m)
#pragma unroll
    for (int r = 0; r < 4; ++r) {
      float v = rp[m][r];
      v += __shfl_xor(v, 1, 16);
      v += __shfl_xor(v, 2, 16);
      v += __shfl_xor(v, 4, 16);
      v += __shfl_xor(v, 8, 16);
      if (lo == 0)
        atomicAdd(&rowsum[grow0 + wrow + m * 16 + hi * 4 + r], v);
    }

  if (sym) {
#pragma unroll
    for (int n = 0; n < 4; ++n) {
      float v = cp[n];
      v += __shfl_xor(v, 16, 64);
      v += __shfl_xor(v, 32, 64);
      if (hi == 0)
        atomicAdd(&rowsum[gcol0 + wcol + n * 16 + lo], v);
    }
  }
}

// Single block: cumsum(rowsum) -> sum(log(neg) - logpos) + js -> out[0]
__global__ __launch_bounds__(256) void final_kernel(
    const float* __restrict__ rowsum, const float* __restrict__ logpos,
    const float* __restrict__ js_acc, float* __restrict__ out) {
  __shared__ float scan[256];
  __shared__ double ds[4];
  const int tid = threadIdx.x;
  float loc[16];
  float run = 0.f;
#pragma unroll
  for (int k = 0; k < 16; ++k) { loc[k] = rowsum[tid * 16 + k]; run += loc[k]; }
  scan[tid] = run;
  __syncthreads();
  for (int d = 1; d < 256; d <<= 1) {
    float add = (tid >= d) ? scan[tid - d] : 0.0f;
    __syncthreads();
    scan[tid] += add;
    __syncthreads();
  }
  float c = scan[tid] - run;  // exclusive prefix
  double acc = 0.0;
#pragma unroll
  for (int k = 0; k < 16; ++k) {
    c += loc[k];
    acc += (double)(logf(c) - logpos[tid * 16 + k]);
  }
#pragma unroll
  for (int m = 32; m >= 1; m >>= 1) acc += __shfl_xor(acc, m, 64);
  if ((tid & 63) == 0) ds[tid >> 6] = acc;
  __syncthreads();
  if (tid == 0) {
    const double nce = ds[0] + ds[1] + ds[2] + ds[3];
    const double js = (double)js_acc[0] / (2.0 * N_ROWS);
    out[0] = (float)(nce + 1.0 * js);
  }
}

extern "C" void kernel_launch(void* const* d_in, const int* in_sizes, int n_in,
                              void* d_out, int out_size, void* d_ws, size_t ws_size,
                              hipStream_t stream) {
  const float* x = (const float*)d_in[0];
  const float* y = (const float*)d_in[1];
  float* out = (float*)d_out;

  char* ws = (char*)d_ws;
  unsigned short* Bb = (unsigned short*)ws;                 // [8192][1024] bf16, 16 MB
  float* inv_n  = (float*)(ws + (size_t)16 * 1024 * 1024);  // 8192
  float* logpos = inv_n + 8192;                             // 4096
  float* rowsum = logpos + 4096;                            // 4096
  float* js_acc = rowsum + 4096;                            // 1

  hipMemsetAsync(rowsum, 0, (4096 + 1) * sizeof(float), stream);
  prep_kernel<<<N_ROWS / 4, 256, 0, stream>>>(x, y, Bb, inv_n, logpos, js_acc);
  gemm_fused<<<1552, 256, 0, stream>>>(Bb, inv_n, rowsum);
  final_kernel<<<1, 256, 0, stream>>>(rowsum, logpos, js_acc, out);
}

// Round 4
// 105.112 us; speedup vs baseline: 1.6242x; 1.4647x over previous
//
#include <hip/hip_runtime.h>
#include <stdint.h>

#define N_ROWS 4096
#define D_DIM  1024
#define KBYTES 2048   // bytes per row in bf16
#define T_TEMP 0.15f

#define AS1 __attribute__((address_space(1)))
#define AS3 __attribute__((address_space(3)))

typedef float  f32x4  __attribute__((ext_vector_type(4)));
typedef __bf16 bf16x8 __attribute__((ext_vector_type(8)));

__device__ __forceinline__ unsigned int f2bf(float f) {
  unsigned u = __float_as_uint(f);
  u += 0x7FFF + ((u >> 16) & 1);   // RNE
  return u >> 16;
}

__device__ __forceinline__ float wsum(float v) {
#pragma unroll
  for (int m = 32; m >= 1; m >>= 1) v += __shfl_xor(v, m, 64);
  return v;
}
__device__ __forceinline__ float wmax(float v) {
#pragma unroll
  for (int m = 32; m >= 1; m >>= 1) v = fmaxf(v, __shfl_xor(v, m, 64));
  return v;
}

// One WAVE per row (no barriers): norms, x.y dot (-> log pos), softmax-JS
// per-row term -> js[row] (no same-address atomics), bf16 casts into
// Bb = [x;y] (8192 x 1024 bf16). Also zeroes rowsum (4 floats per block).
__global__ __launch_bounds__(256) void prep_kernel(
    const float* __restrict__ x, const float* __restrict__ y,
    unsigned short* __restrict__ Bb, float* __restrict__ inv_n,
    float* __restrict__ logpos, float* __restrict__ js,
    float* __restrict__ rowsum) {
  if (threadIdx.x < 4) rowsum[blockIdx.x * 4 + threadIdx.x] = 0.0f;

  const int wid = threadIdx.x >> 6, lane = threadIdx.x & 63;
  const int row = blockIdx.x * 4 + wid;
  const float4* xp = (const float4*)(x + (size_t)row * D_DIM) + lane * 4;
  const float4* yp = (const float4*)(y + (size_t)row * D_DIM) + lane * 4;

  float xv[16], yv[16];
#pragma unroll
  for (int i = 0; i < 4; ++i) {
    float4 a = xp[i], b = yp[i];
    xv[i*4+0]=a.x; xv[i*4+1]=a.y; xv[i*4+2]=a.z; xv[i*4+3]=a.w;
    yv[i*4+0]=b.x; yv[i*4+1]=b.y; yv[i*4+2]=b.z; yv[i*4+3]=b.w;
  }

  float sx2=0.f, sy2=0.f, sxy=0.f, mx=-1e30f, my=-1e30f;
#pragma unroll
  for (int k = 0; k < 16; ++k) {
    sx2 = fmaf(xv[k], xv[k], sx2);
    sy2 = fmaf(yv[k], yv[k], sy2);
    sxy = fmaf(xv[k], yv[k], sxy);
    mx = fmaxf(mx, xv[k]); my = fmaxf(my, yv[k]);
  }
  sx2 = wsum(sx2); sy2 = wsum(sy2); sxy = wsum(sxy);
  mx = wmax(mx);  my = wmax(my);

  float ex[16], ey[16], sex=0.f, sey=0.f;
#pragma unroll
  for (int k = 0; k < 16; ++k) {
    ex[k] = __expf(xv[k] - mx); ey[k] = __expf(yv[k] - my);
    sex += ex[k]; sey += ey[k];
  }
  sex = wsum(sex); sey = wsum(sey);
  const float lsex = __logf(sex), lsey = __logf(sey);
  const float rsex = 1.f / sex,  rsey = 1.f / sey;

  float term = 0.f;
#pragma unroll
  for (int k = 0; k < 16; ++k) {
    float a = ex[k] * rsex, b = ey[k] * rsey;
    float lm = __logf(0.5f * (a + b));
    term += a * ((xv[k] - mx - lsex) - lm) + b * ((yv[k] - my - lsey) - lm);
  }
  term = wsum(term);

  if (lane == 0) {
    const float nx = sqrtf(sx2), ny = sqrtf(sy2);
    inv_n[row] = 1.f / nx;
    inv_n[N_ROWS + row] = 1.f / ny;
    logpos[row] = sxy / fmaxf(nx * ny, 1e-8f) / T_TEMP;  // ln(pos)
    js[row] = term;
  }

  int p[8], q[8];
#pragma unroll
  for (int w = 0; w < 8; ++w) {
    p[w] = f2bf(xv[2*w]) | (f2bf(xv[2*w+1]) << 16);
    q[w] = f2bf(yv[2*w]) | (f2bf(yv[2*w+1]) << 16);
  }
  int4* ox = (int4*)(Bb + (size_t)row * D_DIM + lane * 16);
  int4* oy = (int4*)(Bb + (size_t)(N_ROWS + row) * D_DIM + lane * 16);
  ox[0] = make_int4(p[0], p[1], p[2], p[3]);
  ox[1] = make_int4(p[4], p[5], p[6], p[7]);
  oy[0] = make_int4(q[0], q[1], q[2], q[3]);
  oy[1] = make_int4(q[4], q[5], q[6], q[7]);
}

// ===== 8-phase 256x256 bf16 GEMM, fused exp-cosine row-sum epilogue =====
// A = rows [0,4096) of Bb (=x), B = all 8192 rows (=[x;y]).
// BK=64 split in two k-halves; LDS k-major [buf][kk][256 rows][32 bf16]
// (64B rows, chunk ^= (row>>1)&3 swizzle — R3-measured 0 conflicts).
// 8 waves (2M x 4N), per-wave C = 128x64. 4 phases per K-tile; counted
// vmcnt(4) twice per K-tile (never 0 in main loop).
#define GLL(src, dst) __builtin_amdgcn_global_load_lds((const AS1 void*)(src), (AS3 void*)(dst), 16, 0, 0)
#define ST_A(kt1, h, bufv) do { \
  GLL(gA + (size_t)(kt1)*128 + (h)*64,                        dA + (bufv)*32768 + (h)*16384); \
  GLL(gA + 128*(size_t)KBYTES + (size_t)(kt1)*128 + (h)*64,   dA + (bufv)*32768 + (h)*16384 + 8192); } while(0)
#define ST_B(kt1, h, bufv) do { \
  GLL(gB + (size_t)(kt1)*128 + (h)*64,                        dB + (bufv)*32768 + (h)*16384); \
  GLL(gB + 128*(size_t)KBYTES + (size_t)(kt1)*128 + (h)*64,   dB + (bufv)*32768 + (h)*16384 + 8192); } while(0)
#define RD_A(kk, bufv) do { _Pragma("unroll") \
  for (int m_ = 0; m_ < 8; ++m_) \
    a[m_] = *(const bf16x8*)(lA0 + (bufv)*32768 + (kk)*16384 + m_*1024); } while(0)
#define RD_B(n0, kk, bufv) do { \
  b[(n0)]   = *(const bf16x8*)(lB0 + (bufv)*32768 + (kk)*16384 + ((n0))*1024); \
  b[(n0)+1] = *(const bf16x8*)(lB0 + (bufv)*32768 + (kk)*16384 + ((n0)+1)*1024); } while(0)
#define MM(ch_) do { _Pragma("unroll") \
  for (int m_ = 0; m_ < 8; ++m_) { \
    acc[m_][2*(ch_)]   = __builtin_amdgcn_mfma_f32_16x16x32_bf16(a[m_], b[2*(ch_)],   acc[m_][2*(ch_)],   0, 0, 0); \
    acc[m_][2*(ch_)+1] = __builtin_amdgcn_mfma_f32_16x16x32_bf16(a[m_], b[2*(ch_)+1], acc[m_][2*(ch_)+1], 0, 0, 0); } } while(0)
#define BARR  __builtin_amdgcn_s_barrier()
#define LGKM0 asm volatile("s_waitcnt lgkmcnt(0)")
#define VM4   asm volatile("s_waitcnt vmcnt(4)" ::: "memory")
#define VM0   asm volatile("s_waitcnt vmcnt(0)" ::: "memory")

__global__ __launch_bounds__(512, 2) void gemm_fused(
    const unsigned short* __restrict__ Bb, const float* __restrict__ inv_n,
    float* __restrict__ rowsum) {
  __shared__ __align__(16) unsigned short As[2][2][256][32];
  __shared__ __align__(16) unsigned short Bs[2][2][256][32];
  const int tid = threadIdx.x;
  const int wid = tid >> 6, lane = tid & 63;
  const int lo = lane & 15, hi = lane >> 4;
  const int wm = wid >> 2, wn = wid & 3;

  // chunked XCD swizzle: 512 blocks -> 8 XCD chunks, each an 8x8 tile block
  const int id = blockIdx.x;
  const int u = (id & 7) * 64 + (id >> 3);
  const int ch = u >> 6, lcl = u & 63;
  const int bx = ((ch & 1) << 3) + (lcl >> 3);
  const int by = ((ch >> 1) << 3) + (lcl & 7);
  const int grow0 = bx * 256, gcol0 = by * 256;

  f32x4 acc[8][4] = {};
  bf16x8 a[8], b[4];

  // staging: per-lane global source, chunk pre-swizzled by (row>>1)&3
  const int srow = wid * 16 + (lane >> 2);
  const int gch = (lane & 3) ^ ((lane >> 3) & 3);
  const char* gA = (const char*)Bb + (size_t)(grow0 + srow) * KBYTES + gch * 16;
  const char* gB = (const char*)Bb + (size_t)(gcol0 + srow) * KBYTES + gch * 16;
  char* dA = (char*)As + wid * 1024;   // + buf*32768 + h*16384 (+8192 for j=1)
  char* dB = (char*)Bs + wid * 1024;

  // fragment-read bases (same swizzle on the read side)
  const int xr = (lo >> 1) & 3;
  const char* lA0 = (const char*)As + (wm * 128 + lo) * 64 + ((hi ^ xr) << 4);
  const char* lB0 = (const char*)Bs + (wn * 64  + lo) * 64 + ((hi ^ xr) << 4);

  // prologue: stage tile 0 (u1=A-kh0, u2=B-kh0, u3=A-kh1, u4=B-kh1)
  ST_A(0, 0, 0); ST_B(0, 0, 0); ST_A(0, 1, 0); ST_B(0, 1, 0);
  VM4;   // A-kh0,B-kh0 of tile 0 complete
  BARR;

  for (int kt = 0; kt < 15; ++kt) {
    const int buf = kt & 1, nbuf = buf ^ 1, kn = kt + 1;
    // P1: kk0, col-half 0
    RD_A(0, buf); RD_B(0, 0, buf);
    ST_A(kn, 0, nbuf);
    BARR; LGKM0;
    __builtin_amdgcn_s_setprio(1); MM(0); __builtin_amdgcn_s_setprio(0);
    BARR;
    // P2: kk0, col-half 1
    RD_B(2, 0, buf);
    ST_B(kn, 0, nbuf);
    BARR; LGKM0;
    __builtin_amdgcn_s_setprio(1); MM(1); __builtin_amdgcn_s_setprio(0);
    VM4;   // completes A-kh1,B-kh1 of tile kt (needed at P3)
    BARR;
    // P3: kk1, col-half 0
    RD_A(1, buf); RD_B(0, 1, buf);
    ST_A(kn, 1, nbuf);
    BARR; LGKM0;
    __builtin_amdgcn_s_setprio(1); MM(0); __builtin_amdgcn_s_setprio(0);
    BARR;
    // P4: kk1, col-half 1
    RD_B(2, 1, buf);
    ST_B(kn, 1, nbuf);
    BARR; LGKM0;
    __builtin_amdgcn_s_setprio(1); MM(1); __builtin_amdgcn_s_setprio(0);
    VM4;   // completes A-kh0,B-kh0 of tile kn (needed at next P1)
    BARR;
  }
  // tail K-tile kt=15 (buf=1), no staging
  RD_A(0, 1); RD_B(0, 0, 1);
  BARR; LGKM0;
  __builtin_amdgcn_s_setprio(1); MM(0); __builtin_amdgcn_s_setprio(0);
  BARR;
  RD_B(2, 0, 1);
  BARR; LGKM0;
  __builtin_amdgcn_s_setprio(1); MM(1); __builtin_amdgcn_s_setprio(0);
  VM0;   // drain A-kh1,B-kh1 of tile 15
  BARR;
  RD_A(1, 1); RD_B(0, 1, 1);
  BARR; LGKM0;
  __builtin_amdgcn_s_setprio(1); MM(0); __builtin_amdgcn_s_setprio(0);
  BARR;
  RD_B(2, 1, 1);
  BARR; LGKM0;
  __builtin_amdgcn_s_setprio(1); MM(1); __builtin_amdgcn_s_setprio(0);
  BARR;

  // epilogue: scale -> exp2 -> mask diag -> row-reduce -> atomic
  const float C = 1.4426950408889634f / T_TEMP;   // log2(e)/T
  float invc[4], invr[8][4];
#pragma unroll
  for (int n = 0; n < 4; ++n)
    invc[n] = inv_n[gcol0 + wn * 64 + n * 16 + lo] * C;
#pragma unroll
  for (int m = 0; m < 8; ++m)
#pragma unroll
    for (int r = 0; r < 4; ++r)
      invr[m][r] = inv_n[grow0 + wm * 128 + m * 16 + hi * 4 + r];

  float rp[8][4] = {};
#pragma unroll
  for (int m = 0; m < 8; ++m)
#pragma unroll
    for (int n = 0; n < 4; ++n)
#pragma unroll
      for (int r = 0; r < 4; ++r) {
        const int i = grow0 + wm * 128 + m * 16 + hi * 4 + r;
        const int j = gcol0 + wn * 64 + n * 16 + lo;
        float e2 = exp2f(acc[m][n][r] * invr[m][r] * invc[n]);
        if (j == i || j == i + N_ROWS) e2 = 0.0f;
        rp[m][r] += e2;
      }

#pragma unroll
  for (int m = 0; m < 8; ++m)
#pragma unroll
    for (int r = 0; r < 4; ++r) {
      float v = rp[m][r];
      v += __shfl_xor(v, 1, 16);
      v += __shfl_xor(v, 2, 16);
      v += __shfl_xor(v, 4, 16);
      v += __shfl_xor(v, 8, 16);
      if (lo == 0)
        atomicAdd(&rowsum[grow0 + wm * 128 + m * 16 + hi * 4 + r], v);
    }
}

// Single block: cumsum(rowsum) -> sum(log(neg) - logpos) + sum(js) -> out[0]
__global__ __launch_bounds__(256) void final_kernel(
    const float* __restrict__ rowsum, const float* __restrict__ logpos,
    const float* __restrict__ js, float* __restrict__ out) {
  __shared__ float scan[256];
  __shared__ double ds[4];
  __shared__ float fs[4];
  const int tid = threadIdx.x;
  float loc[16];
  float run = 0.f, jl = 0.f;
#pragma unroll
  for (int k = 0; k < 16; ++k) {
    loc[k] = rowsum[tid * 16 + k];
    run += loc[k];
    jl += js[tid * 16 + k];
  }
  scan[tid] = run;
  __syncthreads();
  for (int d = 1; d < 256; d <<= 1) {
    float add = (tid >= d) ? scan[tid - d] : 0.0f;
    __syncthreads();
    scan[tid] += add;
    __syncthreads();
  }
  float c = scan[tid] - run;  // exclusive prefix
  double acc = 0.0;
#pragma unroll
  for (int k = 0; k < 16; ++k) {
    c += loc[k];
    acc += (double)(logf(c) - logpos[tid * 16 + k]);
  }
#pragma unroll
  for (int m = 32; m >= 1; m >>= 1) {
    acc += __shfl_xor(acc, m, 64);
    jl  += __shfl_xor(jl, m, 64);
  }
  if ((tid & 63) == 0) { ds[tid >> 6] = acc; fs[tid >> 6] = jl; }
  __syncthreads();
  if (tid == 0) {
    const double nce = ds[0] + ds[1] + ds[2] + ds[3];
    const double jst = (double)(fs[0] + fs[1] + fs[2] + fs[3]);
    out[0] = (float)(nce + jst / (2.0 * N_ROWS));
  }
}

extern "C" void kernel_launch(void* const* d_in, const int* in_sizes, int n_in,
                              void* d_out, int out_size, void* d_ws, size_t ws_size,
                              hipStream_t stream) {
  const float* x = (const float*)d_in[0];
  const float* y = (const float*)d_in[1];
  float* out = (float*)d_out;

  char* ws = (char*)d_ws;
  unsigned short* Bb = (unsigned short*)ws;                 // [8192][1024] bf16, 16 MB
  float* inv_n  = (float*)(ws + (size_t)16 * 1024 * 1024);  // 8192
  float* logpos = inv_n + 8192;                             // 4096
  float* rowsum = logpos + 4096;                            // 4096
  float* js     = rowsum + 4096;                            // 4096

  prep_kernel<<<N_ROWS / 4, 256, 0, stream>>>(x, y, Bb, inv_n, logpos, js, rowsum);
  gemm_fused<<<512, 512, 0, stream>>>(Bb, inv_n, rowsum);
  final_kernel<<<1, 256, 0, stream>>>(rowsum, logpos, js, out);
}